// Round 2
// baseline (433.731 us; speedup 1.0000x reference)
//
#include <hip/hip_runtime.h>

// Problem constants: B=16, S=1024, d=1024, H=16, dh=64
#define B_  16
#define S_  1024
#define D_  1024
#define H_  16
#define DH_ 64
#define M_  (B_ * S_)    // 16384 rows in the projection GEMMs
#define BH_ (B_ * H_)    // 256 (b,h) pairs

typedef __attribute__((ext_vector_type(8))) __bf16 bf16x8;
typedef __attribute__((ext_vector_type(4))) float  f32x4;

__device__ __forceinline__ ushort f2bf(float f) {
  unsigned u = __builtin_bit_cast(unsigned, f);
  return (ushort)((u + 0x7FFFu + ((u >> 16) & 1u)) >> 16);
}

__device__ __forceinline__ bf16x8 ld8(const ushort* p) {
  return *(const bf16x8*)p;
}

__device__ __forceinline__ float fast_exp2(float x) {
  return __builtin_amdgcn_exp2f(x);  // v_exp_f32
}

__device__ __forceinline__ void gl_lds16(const void* g, void* s) {
  __builtin_amdgcn_global_load_lds((__attribute__((address_space(1))) void*)g,
                                   (__attribute__((address_space(3))) void*)s,
                                   16, 0, 0);
}

#define FENCE() asm volatile("" ::: "memory")

// ---------------------------------------------------------------- fp32->bf16
__global__ void cvt4(const float* __restrict__ s, ushort* __restrict__ d, int n4) {
  int i = blockIdx.x * 256 + threadIdx.x;
  if (i < n4) {
    const float4 v = ((const float4*)s)[i];
    ushort4 o;
    o.x = f2bf(v.x); o.y = f2bf(v.y); o.z = f2bf(v.z); o.w = f2bf(v.w);
    ((ushort4*)d)[i] = o;
  }
}

// =====================================================================
// 256x256 tile, BK=64, 8 waves (2M x 4N), 8-phase pipelined GEMM core.
// LDS: 2 bufs x (A 256x64 + B 256x64) bf16 = 128 KiB, XOR-swizzled at
// 16B-block granularity (pb = b ^ (row&7)); swizzle realized by
// pre-swizzling the *global* source of global_load_lds (linear LDS dest)
// and applying the same XOR on ds_read addresses (both-sides rule).
// Counted vmcnt(4) once per K-tile group keeps 2 half-tiles in flight
// across barriers; never drains to 0 in steady state.
// Verified r1: SQ_LDS_BANK_CONFLICT = 0, passed, MfmaUtil 30%.
// =====================================================================
#define NT_ 16  // K = 1024 = 16 x BK(64)

// stage one half-tile (128 rows x 64 cols) = 2 x global_load_lds_dwordx4/thread
__device__ __forceinline__ void stg2(const ushort* __restrict__ src, ushort* lds,
                                     int bufop, int half, int kt,
                                     int wid, int lane, int rj0, int gcol) {
  gl_lds16(src + (size_t)(half * 128 + rj0) * 1024 + kt * 64 + gcol,
           lds + bufop * 16384 + half * 8192 + wid * 512 + lane * 8);
  gl_lds16(src + (size_t)(half * 128 + rj0 + 64) * 1024 + kt * 64 + gcol,
           lds + bufop * 16384 + half * 8192 + (wid + 8) * 512 + lane * 8);
}

__device__ __forceinline__ void gemm256_core(const ushort* __restrict__ baseA,
                                             const ushort* __restrict__ baseB,
                                             ushort* lds, f32x4 (&acc)[8][4]) {
  const int wid = threadIdx.x >> 6, lane = threadIdx.x & 63;
  const int lr = lane & 15, qd = lane >> 4;
  const int wr = wid >> 2, wc = wid & 3;
  const int gcol = ((lane & 7) ^ (lane >> 3)) << 3;  // pre-swizzled global col
  const int rj0  = wid * 8 + (lane >> 3);
  const int sw = lr & 7;
  const int colsw0 = (qd ^ sw) << 3;        // kk=0 swizzled 16B block
  const int colsw1 = ((4 + qd) ^ sw) << 3;  // kk=1

  // prologue: tile0 (A+B) -> buf0 ; B(tile1) -> buf1  (queue: [A0h0,A0h1,B0h0,B0h1,B1h0,B1h1])
  stg2(baseA, lds, 0, 0, 0, wid, lane, rj0, gcol);
  stg2(baseA, lds, 0, 1, 0, wid, lane, rj0, gcol);
  stg2(baseB, lds, 1, 0, 0, wid, lane, rj0, gcol);
  stg2(baseB, lds, 1, 1, 0, wid, lane, rj0, gcol);
  stg2(baseB, lds, 3, 0, 1, wid, lane, rj0, gcol);
  stg2(baseB, lds, 3, 1, 1, wid, lane, rj0, gcol);
  asm volatile("s_waitcnt vmcnt(4)" ::: "memory");  // tile0 landed; B(1) in flight
  FENCE(); __builtin_amdgcn_s_barrier(); FENCE();

#pragma unroll 1
  for (int t = 0; t < NT_; ++t) {
    const int cur = t & 1, nxt = cur ^ 1;
    const int cA = cur * 32768, cB = cA + 16384;
    bf16x8 bfr[4][2], afr[2][2];

#define LDA_(p)                                                                   \
    afr[0][0] = ld8(lds + cA + (wr * 128 + (2*(p)    ) * 16 + lr) * 64 + colsw0); \
    afr[0][1] = ld8(lds + cA + (wr * 128 + (2*(p)    ) * 16 + lr) * 64 + colsw1); \
    afr[1][0] = ld8(lds + cA + (wr * 128 + (2*(p) + 1) * 16 + lr) * 64 + colsw0); \
    afr[1][1] = ld8(lds + cA + (wr * 128 + (2*(p) + 1) * 16 + lr) * 64 + colsw1);

#define MFMA_(p)                                                             \
    FENCE(); __builtin_amdgcn_s_barrier();                                   \
    asm volatile("s_waitcnt lgkmcnt(0)" ::: "memory");                       \
    __builtin_amdgcn_s_setprio(1);                                           \
    _Pragma("unroll")                                                        \
    for (int j = 0; j < 4; j++) {                                            \
      acc[2*(p)  ][j] = __builtin_amdgcn_mfma_f32_16x16x32_bf16(afr[0][0], bfr[j][0], acc[2*(p)  ][j], 0, 0, 0); \
      acc[2*(p)  ][j] = __builtin_amdgcn_mfma_f32_16x16x32_bf16(afr[0][1], bfr[j][1], acc[2*(p)  ][j], 0, 0, 0); \
      acc[2*(p)+1][j] = __builtin_amdgcn_mfma_f32_16x16x32_bf16(afr[1][0], bfr[j][0], acc[2*(p)+1][j], 0, 0, 0); \
      acc[2*(p)+1][j] = __builtin_amdgcn_mfma_f32_16x16x32_bf16(afr[1][1], bfr[j][1], acc[2*(p)+1][j], 0, 0, 0); \
    }                                                                        \
    __builtin_amdgcn_s_setprio(0);

#define CLOSE_() FENCE(); __builtin_amdgcn_s_barrier(); FENCE();

    // ---- phase 0: read B-frags (tile t fully landed) + A m{0,1}; stage A-h0(t+1)
#pragma unroll
    for (int j = 0; j < 4; j++) {
      bfr[j][0] = ld8(lds + cB + (wc * 64 + j * 16 + lr) * 64 + colsw0);
      bfr[j][1] = ld8(lds + cB + (wc * 64 + j * 16 + lr) * 64 + colsw1);
    }
    LDA_(0);
    if (t + 1 < NT_) stg2(baseA, lds, nxt * 2, 0, t + 1, wid, lane, rj0, gcol);
    MFMA_(0); CLOSE_();
    // ---- phase 1: A m{2,3}; stage A-h1(t+1) then B-h0(t+2) (order matters for vmcnt)
    LDA_(1);
    if (t + 1 < NT_) stg2(baseA, lds, nxt * 2, 1, t + 1, wid, lane, rj0, gcol);
    if (t + 2 < NT_) stg2(baseB, lds, cur * 2 + 1, 0, t + 2, wid, lane, rj0, gcol);
    MFMA_(1); CLOSE_();
    // ---- phase 2: A m{4,5}; stage B-h1(t+2)
    LDA_(2);
    if (t + 2 < NT_) stg2(baseB, lds, cur * 2 + 1, 1, t + 2, wid, lane, rj0, gcol);
    MFMA_(2); CLOSE_();
    // ---- phase 3: A m{6,7}; group-end counted vmcnt (tile t+1 landed, B(t+2) in flight)
    LDA_(3);
    MFMA_(3);
    if (t <= NT_ - 3) { asm volatile("s_waitcnt vmcnt(4)" ::: "memory"); }
    else              { asm volatile("s_waitcnt vmcnt(0)" ::: "memory"); }
    CLOSE_();
#undef LDA_
#undef MFMA_
#undef CLOSE_
  }
}

// ------------------------------------------------------- fused QKV projection
// One GEMM over concatenated weights Wqkv [3072,1024]. Epilogue routes by
// n-block: proj 0 -> Q [B,H,S,dh], 1 -> K [B,H,S,dh], 2 -> V^T [B,H,dh,S].
// Block order: XCD-chunked, then 4x4 (mb x nb) supertiles within each XCD so
// the concurrent 32-block working set is ~A 2MB + B 2MB (fits 4MB L2) instead
// of sweeping all 12 B-panels (6MB) per 12 blocks.
__global__ __launch_bounds__(512, 2) void gemm_qkv(
    const ushort* __restrict__ A, const ushort* __restrict__ Wqkv,
    const float* __restrict__ bqp, const float* __restrict__ bkp,
    const float* __restrict__ bvp, ushort* __restrict__ qO,
    ushort* __restrict__ kO, ushort* __restrict__ vtO) {
  __shared__ ushort lds[65536];  // 128 KiB
  const int orig = blockIdx.x;            // 768 wgs
  const int xcd = orig & 7;               // dispatch round-robins XCDs
  const int idx = orig >> 3;              // 0..95 within XCD
  const int sidx = idx >> 4, wit = idx & 15;   // 6 supertiles of 16 blocks
  const int smb = sidx & 1, snb = sidx >> 1;   // supertile coords (2 x 3)
  const int mb = (xcd << 3) + (smb << 2) + (wit & 3);  // 0..63
  const int nb = (snb << 2) + (wit >> 2);              // 0..11
  const int wid = threadIdx.x >> 6, lane = threadIdx.x & 63;
  const int lr = lane & 15, qd = lane >> 4;
  const int wr = wid >> 2, wc = wid & 3;

  f32x4 acc[8][4];
  const f32x4 z = {0.f, 0.f, 0.f, 0.f};
#pragma unroll
  for (int i = 0; i < 8; i++)
#pragma unroll
    for (int j = 0; j < 4; j++) acc[i][j] = z;

  gemm256_core(A + (size_t)(mb * 256) * 1024, Wqkv + (size_t)(nb * 256) * 1024, lds, acc);

  const int proj = nb >> 2;  // block-uniform
  const float* bias = (proj == 0) ? bqp : (proj == 1) ? bkp : bvp;
  ushort* outH = (proj == 0) ? qO : (proj == 1) ? kO : vtO;
  const int m0 = mb * 256;

#pragma unroll
  for (int j = 0; j < 4; j++) {
    const int nn = (nb * 256 + wc * 64 + j * 16 + lr) & 1023;
    const float bv = bias[nn];
    const int h = nn >> 6, dc = nn & 63;
#pragma unroll
    for (int i = 0; i < 8; i++) {
      const f32x4 v = acc[i][j];
      const int mbase = m0 + wr * 128 + i * 16 + qd * 4;
      const int b = mbase >> 10, s0 = mbase & 1023;
      if (proj < 2) {
#pragma unroll
        for (int r = 0; r < 4; r++)
          outH[((size_t)(b * H_ + h) * S_ + s0 + r) * DH_ + dc] = f2bf(v[r] + bv);
      } else {
        uint2 pk;
        pk.x = (uint)f2bf(v[0] + bv) | ((uint)f2bf(v[1] + bv) << 16);
        pk.y = (uint)f2bf(v[2] + bv) | ((uint)f2bf(v[3] + bv) << 16);
        *(uint2*)&outH[((size_t)(b * H_ + h) * DH_ + dc) * S_ + s0] = pk;
      }
    }
  }
}

// ------------------------------------------------------------- output GEMM
__global__ __launch_bounds__(512, 2) void gemm_out(
    const ushort* __restrict__ A, const ushort* __restrict__ W,
    const float* __restrict__ bias, float* __restrict__ outF) {
  __shared__ ushort lds[65536];
  int wg = blockIdx.x;
  wg = (wg & 7) * 32 + (wg >> 3);  // 256 wgs, 32/XCD (all concurrent, 1 round)
  const int mb = wg >> 2, nb = wg & 3;
  const int wid = threadIdx.x >> 6, lane = threadIdx.x & 63;
  const int lr = lane & 15, qd = lane >> 4;
  const int wr = wid >> 2, wc = wid & 3;

  f32x4 acc[8][4];
  const f32x4 z = {0.f, 0.f, 0.f, 0.f};
#pragma unroll
  for (int i = 0; i < 8; i++)
#pragma unroll
    for (int j = 0; j < 4; j++) acc[i][j] = z;

  gemm256_core(A + (size_t)(mb * 256) * 1024, W + (size_t)(nb * 256) * 1024, lds, acc);

#pragma unroll
  for (int j = 0; j < 4; j++) {
    const int n = nb * 256 + wc * 64 + j * 16 + lr;
    const float bv = bias[n];
#pragma unroll
    for (int i = 0; i < 8; i++) {
      const f32x4 v = acc[i][j];
      const int m = mb * 256 + wr * 128 + i * 16 + qd * 4;
#pragma unroll
      for (int r = 0; r < 4; r++) outF[(size_t)(m + r) * D_ + n] = v[r] + bv;
    }
  }
}

// --------------------------------------------------------------- attention
// Barrier-free causal flash attention (transposed-score formulation).
// r2 restructure: 32-row q-tiles (was 64) to cut per-wave VGPR state
// (acc[4][2]+bq[2][2] ~ 110-125 regs) and double total parallelism:
// BH x 16 waves = 4096 waves = 16/CU = up to 4/SIMD (was 2/SIMD, VGPR-capped).
// Balanced pairing: wave p handles q-tiles p and 31-p -> (p+1)+(32-p) = 33
// k-iters for every wave. Grid (4, BH): 1024 blocks of 4 waves.
#define PSTR 40  // LDS row stride (ushorts): 80B, 16B-aligned
__global__ __launch_bounds__(256, 3) void attn_kernel(
    const ushort* __restrict__ Q, const ushort* __restrict__ K,
    const ushort* __restrict__ Vt, ushort* __restrict__ O) {
  __shared__ ushort lP[4][32 * PSTR];
  const int bh = blockIdx.y;
  const int w = threadIdx.x >> 6, l = threadIdx.x & 63;
  const int lr = l & 15, qd = l >> 4;
  const int p = blockIdx.x * 4 + w;  // 0..15
  const size_t base = (size_t)bh * (S_ * DH_);
  const ushort* Qb = Q + base;
  const ushort* Kb = K + base;
  const ushort* Vb = Vt + (size_t)bh * (DH_ * S_);
  ushort* myP = &lP[w][0];
  const int b = bh >> 4, h = bh & 15;
  const float C = 0.18033688011112042f;  // log2(e) / sqrt(dh)
  const f32x4 z = {0.f, 0.f, 0.f, 0.f};

#pragma unroll 1
  for (int tt = 0; tt < 2; tt++) {
    const int q0 = (tt == 0 ? p : 31 - p) * 32;

    // Q B-fragments: B[n=q(lane&15)][k=dh qd*8+j]
    bf16x8 bq[2][2];
#pragma unroll
    for (int qt = 0; qt < 2; qt++)
#pragma unroll
      for (int kc = 0; kc < 2; kc++)
        bq[qt][kc] = ld8(Qb + (size_t)(q0 + qt * 16 + lr) * DH_ + kc * 32 + qd * 8);

    f32x4 acc[4][2];  // [dh tile][q tile], O^T C-layout
#pragma unroll
    for (int i = 0; i < 4; i++)
#pragma unroll
      for (int j = 0; j < 2; j++) acc[i][j] = z;
    float li[2] = {0.f, 0.f};

    for (int kb = 0; kb < q0 + 32; kb += 32) {
      // K A-frags: A[m=key local][k=dh]
      bf16x8 ak[2][2];
#pragma unroll
      for (int kt = 0; kt < 2; kt++)
#pragma unroll
        for (int kc = 0; kc < 2; kc++)
          ak[kt][kc] = ld8(Kb + (size_t)(kb + kt * 16 + lr) * DH_ + kc * 32 + qd * 8);
      // V A-frags: A[m=dh local][k=key]
      bf16x8 av[4];
#pragma unroll
      for (int dt = 0; dt < 4; dt++)
        av[dt] = ld8(Vb + (size_t)(dt * 16 + lr) * S_ + kb + qd * 8);

      const bool diag = (kb + 31 >= q0);  // wave-uniform (last iter only)
#pragma unroll
      for (int kt = 0; kt < 2; kt++) {
        const int keyb = kb + kt * 16 + qd * 4;
#pragma unroll
        for (int qt = 0; qt < 2; qt++) {
          f32x4 s = z;
          s = __builtin_amdgcn_mfma_f32_16x16x32_bf16(ak[kt][0], bq[qt][0], s, 0, 0, 0);
          s = __builtin_amdgcn_mfma_f32_16x16x32_bf16(ak[kt][1], bq[qt][1], s, 0, 0, 0);
          const int qq = q0 + qt * 16 + lr;
          float e0 = s[0] * C, e1 = s[1] * C, e2 = s[2] * C, e3 = s[3] * C;
          if (diag) {
            e0 = (keyb + 0 <= qq) ? e0 : -1e30f;
            e1 = (keyb + 1 <= qq) ? e1 : -1e30f;
            e2 = (keyb + 2 <= qq) ? e2 : -1e30f;
            e3 = (keyb + 3 <= qq) ? e3 : -1e30f;
          }
          const float p0 = fast_exp2(e0), p1 = fast_exp2(e1);
          const float p2 = fast_exp2(e2), p3 = fast_exp2(e3);
          li[qt] += (p0 + p1) + (p2 + p3);
          const uint d0 = __builtin_amdgcn_perm(__builtin_bit_cast(uint, p1),
                                                __builtin_bit_cast(uint, p0), 0x07060302u);
          const uint d1 = __builtin_amdgcn_perm(__builtin_bit_cast(uint, p3),
                                                __builtin_bit_cast(uint, p2), 0x07060302u);
          uint2 pk; pk.x = d0; pk.y = d1;
          *(uint2*)(myP + (qt * 16 + lr) * PSTR + kt * 16 + qd * 4) = pk;
        }
      }
      // PV: B[n=q][k=key] from wave-private LDS
#pragma unroll
      for (int qt = 0; qt < 2; qt++) {
        const bf16x8 bp = ld8(myP + (qt * 16 + lr) * PSTR + qd * 8);
#pragma unroll
        for (int dt = 0; dt < 4; dt++)
          acc[dt][qt] = __builtin_amdgcn_mfma_f32_16x16x32_bf16(av[dt], bp, acc[dt][qt], 0, 0, 0);
      }
    }

    // epilogue for this tile
#pragma unroll
    for (int qt = 0; qt < 2; qt++) {
      float s = li[qt];
      s += __shfl_xor(s, 16);
      s += __shfl_xor(s, 32);
      const float inv = 1.f / s;
      const int q = q0 + qt * 16 + lr;
      ushort* orow = O + ((size_t)(b * S_ + q) * D_) + h * DH_ + qd * 4;
#pragma unroll
      for (int dt = 0; dt < 4; dt++) {
        const f32x4 v = acc[dt][qt];
        uint2 pk;
        pk.x = (uint)f2bf(v[0] * inv) | ((uint)f2bf(v[1] * inv) << 16);
        pk.y = (uint)f2bf(v[2] * inv) | ((uint)f2bf(v[3] * inv) << 16);
        *(uint2*)(orow + dt * 16) = pk;
      }
    }
  }
}

// ------------------------------------------------------------------- launch
extern "C" void kernel_launch(void* const* d_in, const int* in_sizes, int n_in,
                              void* d_out, int out_size, void* d_ws, size_t ws_size,
                              hipStream_t stream) {
  const float* x  = (const float*)d_in[0];
  const float* Wq = (const float*)d_in[1];
  const float* bq = (const float*)d_in[2];
  const float* Wk = (const float*)d_in[3];
  const float* bk = (const float*)d_in[4];
  const float* Wv = (const float*)d_in[5];
  const float* bv = (const float*)d_in[6];
  const float* Wo = (const float*)d_in[7];
  const float* bo = (const float*)d_in[8];
  float* out = (float*)d_out;

  char* ws = (char*)d_ws;
  ushort* xb   = (ushort*)(ws);                 // x bf16            32 MB
  ushort* qb   = (ushort*)(ws + 33554432);      // Q [B,H,S,dh]      32 MB
  ushort* kb   = (ushort*)(ws + 67108864);      // K [B,H,S,dh]      32 MB
  ushort* vtb  = (ushort*)(ws + 100663296);     // V [B,H,dh,S]      32 MB
  ushort* attn = (ushort*)(ws + 134217728);     // attn out [B,S,d]  32 MB
  ushort* wqb  = (ushort*)(ws + 167772160);     // Wq|Wk|Wv contiguous: [3072,1024]
  ushort* wkb  = (ushort*)(ws + 169869312);
  ushort* wvb  = (ushort*)(ws + 171966464);
  ushort* wob  = (ushort*)(ws + 174063616);

  cvt4<<<16384, 256, 0, stream>>>(x,  xb,  4194304);
  cvt4<<<1024,  256, 0, stream>>>(Wq, wqb, 262144);
  cvt4<<<1024,  256, 0, stream>>>(Wk, wkb, 262144);
  cvt4<<<1024,  256, 0, stream>>>(Wv, wvb, 262144);
  cvt4<<<1024,  256, 0, stream>>>(Wo, wob, 262144);

  gemm_qkv<<<768, 512, 0, stream>>>(xb, wqb, bq, bk, bv, qb, kb, vtb);

  attn_kernel<<<dim3(4, BH_), 256, 0, stream>>>(qb, kb, vtb, attn);

  gemm_out<<<256, 512, 0, stream>>>(attn, wob, bo, out);
}

// Round 3
// 414.468 us; speedup vs baseline: 1.0465x; 1.0465x over previous
//
#include <hip/hip_runtime.h>

// Problem constants: B=16, S=1024, d=1024, H=16, dh=64
#define B_  16
#define S_  1024
#define D_  1024
#define H_  16
#define DH_ 64
#define M_  (B_ * S_)    // 16384 rows in the projection GEMMs
#define BH_ (B_ * H_)    // 256 (b,h) pairs

typedef __attribute__((ext_vector_type(8))) __bf16 bf16x8;
typedef __attribute__((ext_vector_type(4))) float  f32x4;

__device__ __forceinline__ ushort f2bf(float f) {
  unsigned u = __builtin_bit_cast(unsigned, f);
  return (ushort)((u + 0x7FFFu + ((u >> 16) & 1u)) >> 16);
}

__device__ __forceinline__ bf16x8 ld8(const ushort* p) {
  return *(const bf16x8*)p;
}

__device__ __forceinline__ float fast_exp2(float x) {
  return __builtin_amdgcn_exp2f(x);  // v_exp_f32
}

__device__ __forceinline__ void gl_lds16(const void* g, void* s) {
  __builtin_amdgcn_global_load_lds((__attribute__((address_space(1))) void*)g,
                                   (__attribute__((address_space(3))) void*)s,
                                   16, 0, 0);
}

#define FENCE() asm volatile("" ::: "memory")

// ---------------------------------------------------------------- fp32->bf16
__global__ void cvt4(const float* __restrict__ s, ushort* __restrict__ d, int n4) {
  int i = blockIdx.x * 256 + threadIdx.x;
  if (i < n4) {
    const float4 v = ((const float4*)s)[i];
    ushort4 o;
    o.x = f2bf(v.x); o.y = f2bf(v.y); o.z = f2bf(v.z); o.w = f2bf(v.w);
    ((ushort4*)d)[i] = o;
  }
}

// =====================================================================
// 256x256 tile, BK=64, 8 waves (2M x 4N), 8-phase pipelined GEMM core.
// Verified r1: SQ_LDS_BANK_CONFLICT = 0, passed, 143.6 us on qkv.
// =====================================================================
#define NT_ 16  // K = 1024 = 16 x BK(64)

// stage one half-tile (128 rows x 64 cols) = 2 x global_load_lds_dwordx4/thread
__device__ __forceinline__ void stg2(const ushort* __restrict__ src, ushort* lds,
                                     int bufop, int half, int kt,
                                     int wid, int lane, int rj0, int gcol) {
  gl_lds16(src + (size_t)(half * 128 + rj0) * 1024 + kt * 64 + gcol,
           lds + bufop * 16384 + half * 8192 + wid * 512 + lane * 8);
  gl_lds16(src + (size_t)(half * 128 + rj0 + 64) * 1024 + kt * 64 + gcol,
           lds + bufop * 16384 + half * 8192 + (wid + 8) * 512 + lane * 8);
}

__device__ __forceinline__ void gemm256_core(const ushort* __restrict__ baseA,
                                             const ushort* __restrict__ baseB,
                                             ushort* lds, f32x4 (&acc)[8][4]) {
  const int wid = threadIdx.x >> 6, lane = threadIdx.x & 63;
  const int lr = lane & 15, qd = lane >> 4;
  const int wr = wid >> 2, wc = wid & 3;
  const int gcol = ((lane & 7) ^ (lane >> 3)) << 3;  // pre-swizzled global col
  const int rj0  = wid * 8 + (lane >> 3);
  const int sw = lr & 7;
  const int colsw0 = (qd ^ sw) << 3;        // kk=0 swizzled 16B block
  const int colsw1 = ((4 + qd) ^ sw) << 3;  // kk=1

  // prologue: tile0 (A+B) -> buf0 ; B(tile1) -> buf1
  stg2(baseA, lds, 0, 0, 0, wid, lane, rj0, gcol);
  stg2(baseA, lds, 0, 1, 0, wid, lane, rj0, gcol);
  stg2(baseB, lds, 1, 0, 0, wid, lane, rj0, gcol);
  stg2(baseB, lds, 1, 1, 0, wid, lane, rj0, gcol);
  stg2(baseB, lds, 3, 0, 1, wid, lane, rj0, gcol);
  stg2(baseB, lds, 3, 1, 1, wid, lane, rj0, gcol);
  asm volatile("s_waitcnt vmcnt(4)" ::: "memory");  // tile0 landed; B(1) in flight
  FENCE(); __builtin_amdgcn_s_barrier(); FENCE();

#pragma unroll 1
  for (int t = 0; t < NT_; ++t) {
    const int cur = t & 1, nxt = cur ^ 1;
    const int cA = cur * 32768, cB = cA + 16384;
    bf16x8 bfr[4][2], afr[2][2];

#define LDA_(p)                                                                   \
    afr[0][0] = ld8(lds + cA + (wr * 128 + (2*(p)    ) * 16 + lr) * 64 + colsw0); \
    afr[0][1] = ld8(lds + cA + (wr * 128 + (2*(p)    ) * 16 + lr) * 64 + colsw1); \
    afr[1][0] = ld8(lds + cA + (wr * 128 + (2*(p) + 1) * 16 + lr) * 64 + colsw0); \
    afr[1][1] = ld8(lds + cA + (wr * 128 + (2*(p) + 1) * 16 + lr) * 64 + colsw1);

#define MFMA_(p)                                                             \
    FENCE(); __builtin_amdgcn_s_barrier();                                   \
    asm volatile("s_waitcnt lgkmcnt(0)" ::: "memory");                       \
    __builtin_amdgcn_s_setprio(1);                                           \
    _Pragma("unroll")                                                        \
    for (int j = 0; j < 4; j++) {                                            \
      acc[2*(p)  ][j] = __builtin_amdgcn_mfma_f32_16x16x32_bf16(afr[0][0], bfr[j][0], acc[2*(p)  ][j], 0, 0, 0); \
      acc[2*(p)  ][j] = __builtin_amdgcn_mfma_f32_16x16x32_bf16(afr[0][1], bfr[j][1], acc[2*(p)  ][j], 0, 0, 0); \
      acc[2*(p)+1][j] = __builtin_amdgcn_mfma_f32_16x16x32_bf16(afr[1][0], bfr[j][0], acc[2*(p)+1][j], 0, 0, 0); \
      acc[2*(p)+1][j] = __builtin_amdgcn_mfma_f32_16x16x32_bf16(afr[1][1], bfr[j][1], acc[2*(p)+1][j], 0, 0, 0); \
    }                                                                        \
    __builtin_amdgcn_s_setprio(0);

#define CLOSE_() FENCE(); __builtin_amdgcn_s_barrier(); FENCE();

    // ---- phase 0: read B-frags (tile t fully landed) + A m{0,1}; stage A-h0(t+1)
#pragma unroll
    for (int j = 0; j < 4; j++) {
      bfr[j][0] = ld8(lds + cB + (wc * 64 + j * 16 + lr) * 64 + colsw0);
      bfr[j][1] = ld8(lds + cB + (wc * 64 + j * 16 + lr) * 64 + colsw1);
    }
    LDA_(0);
    if (t + 1 < NT_) stg2(baseA, lds, nxt * 2, 0, t + 1, wid, lane, rj0, gcol);
    MFMA_(0); CLOSE_();
    // ---- phase 1: A m{2,3}; stage A-h1(t+1) then B-h0(t+2)
    LDA_(1);
    if (t + 1 < NT_) stg2(baseA, lds, nxt * 2, 1, t + 1, wid, lane, rj0, gcol);
    if (t + 2 < NT_) stg2(baseB, lds, cur * 2 + 1, 0, t + 2, wid, lane, rj0, gcol);
    MFMA_(1); CLOSE_();
    // ---- phase 2: A m{4,5}; stage B-h1(t+2)
    LDA_(2);
    if (t + 2 < NT_) stg2(baseB, lds, cur * 2 + 1, 1, t + 2, wid, lane, rj0, gcol);
    MFMA_(2); CLOSE_();
    // ---- phase 3: A m{6,7}; group-end counted vmcnt
    LDA_(3);
    MFMA_(3);
    if (t <= NT_ - 3) { asm volatile("s_waitcnt vmcnt(4)" ::: "memory"); }
    else              { asm volatile("s_waitcnt vmcnt(0)" ::: "memory"); }
    CLOSE_();
#undef LDA_
#undef MFMA_
#undef CLOSE_
  }
}

// ------------------------------------------------------- fused QKV projection
// r1 mapping restored (supertile experiment regressed: write locality loss).
__global__ __launch_bounds__(512, 2) void gemm_qkv(
    const ushort* __restrict__ A, const ushort* __restrict__ Wqkv,
    const float* __restrict__ bqp, const float* __restrict__ bkp,
    const float* __restrict__ bvp, ushort* __restrict__ qO,
    ushort* __restrict__ kO, ushort* __restrict__ vtO) {
  __shared__ ushort lds[65536];  // 128 KiB
  int wg = blockIdx.x;
  wg = (wg & 7) * 96 + (wg >> 3);  // XCD swizzle: 768 wgs, 96/XCD
  const int mb = wg / 12, nb = wg % 12;
  const int wid = threadIdx.x >> 6, lane = threadIdx.x & 63;
  const int lr = lane & 15, qd = lane >> 4;
  const int wr = wid >> 2, wc = wid & 3;

  f32x4 acc[8][4];
  const f32x4 z = {0.f, 0.f, 0.f, 0.f};
#pragma unroll
  for (int i = 0; i < 8; i++)
#pragma unroll
    for (int j = 0; j < 4; j++) acc[i][j] = z;

  gemm256_core(A + (size_t)(mb * 256) * 1024, Wqkv + (size_t)(nb * 256) * 1024, lds, acc);

  const int proj = nb >> 2;  // block-uniform
  const float* bias = (proj == 0) ? bqp : (proj == 1) ? bkp : bvp;
  ushort* outH = (proj == 0) ? qO : (proj == 1) ? kO : vtO;
  const int m0 = mb * 256;

#pragma unroll
  for (int j = 0; j < 4; j++) {
    const int nn = (nb * 256 + wc * 64 + j * 16 + lr) & 1023;
    const float bv = bias[nn];
    const int h = nn >> 6, dc = nn & 63;
#pragma unroll
    for (int i = 0; i < 8; i++) {
      const f32x4 v = acc[i][j];
      const int mbase = m0 + wr * 128 + i * 16 + qd * 4;
      const int b = mbase >> 10, s0 = mbase & 1023;
      if (proj < 2) {
#pragma unroll
        for (int r = 0; r < 4; r++)
          outH[((size_t)(b * H_ + h) * S_ + s0 + r) * DH_ + dc] = f2bf(v[r] + bv);
      } else {
        uint2 pk;
        pk.x = (uint)f2bf(v[0] + bv) | ((uint)f2bf(v[1] + bv) << 16);
        pk.y = (uint)f2bf(v[2] + bv) | ((uint)f2bf(v[3] + bv) << 16);
        *(uint2*)&outH[((size_t)(b * H_ + h) * DH_ + dc) * S_ + s0] = pk;
      }
    }
  }
}

// ------------------------------------------------------------- output GEMM
__global__ __launch_bounds__(512, 2) void gemm_out(
    const ushort* __restrict__ A, const ushort* __restrict__ W,
    const float* __restrict__ bias, float* __restrict__ outF) {
  __shared__ ushort lds[65536];
  int wg = blockIdx.x;
  wg = (wg & 7) * 32 + (wg >> 3);  // 256 wgs, 32/XCD
  const int mb = wg >> 2, nb = wg & 3;
  const int wid = threadIdx.x >> 6, lane = threadIdx.x & 63;
  const int lr = lane & 15, qd = lane >> 4;
  const int wr = wid >> 2, wc = wid & 3;

  f32x4 acc[8][4];
  const f32x4 z = {0.f, 0.f, 0.f, 0.f};
#pragma unroll
  for (int i = 0; i < 8; i++)
#pragma unroll
    for (int j = 0; j < 4; j++) acc[i][j] = z;

  gemm256_core(A + (size_t)(mb * 256) * 1024, W + (size_t)(nb * 256) * 1024, lds, acc);

#pragma unroll
  for (int j = 0; j < 4; j++) {
    const int n = nb * 256 + wc * 64 + j * 16 + lr;
    const float bv = bias[n];
#pragma unroll
    for (int i = 0; i < 8; i++) {
      const f32x4 v = acc[i][j];
      const int m = mb * 256 + wr * 128 + i * 16 + qd * 4;
#pragma unroll
      for (int r = 0; r < 4; r++) outF[(size_t)(m + r) * D_ + n] = v[r] + bv;
    }
  }
}

// --------------------------------------------------------------- attention
// r3 restructure: LDS-staged K/V flash attention.
// One block per (bh, q-half): grid (2, BH) = 512 blocks x 512 thr (8 waves).
// Per 64-key step, K-tile (64x64) and V^T-tile (64x64) are staged into LDS
// via global_load_lds (1 instr/thread each), triple-buffered, issued 2 steps
// ahead with counted vmcnt(2) (never drains in steady state). XOR swizzle at
// 16B-block granularity: pre-swizzled GLOBAL source + swizzled ds_read
// (both-sides rule) -> conflict-free b128 reads.
// Each wave owns two 32-row q-tiles with causally balanced pairing:
// half A (q 0..511): tiles {w, 15-w} -> 9 active tile-steps per wave;
// half B (q 512..1023): tiles {16+w, 31-w} -> 25 each. Global K/V traffic
// drops 557 MB -> ~96 MB and in-loop load latency becomes LDS-class.
#define PSTR_ 72  // P row stride in ushorts (144B): 16B-aligned, conflict-light
__global__ __launch_bounds__(512, 2) void attn_kernel(
    const ushort* __restrict__ Q, const ushort* __restrict__ K,
    const ushort* __restrict__ Vt, ushort* __restrict__ O) {
  __shared__ ushort lK[3][4096];      // 3 x 8KB K tiles [key][dh]
  __shared__ ushort lV[3][4096];      // 3 x 8KB V^T tiles [dh][key]
  __shared__ ushort lP[8][32 * PSTR_];// wave-private P scratch
  const int bh = blockIdx.y, half = blockIdx.x;
  const int tid = threadIdx.x;
  const int w = tid >> 6, l = tid & 63;
  const int lr = l & 15, qd = l >> 4;
  const int NS = 8 + half * 8;        // staged 64-key steps
  const size_t base = (size_t)bh * (S_ * DH_);
  const ushort* Qb = Q + base;
  const ushort* Kb = K + base;
  const ushort* Vb = Vt + (size_t)bh * (DH_ * S_);
  ushort* myP = &lP[w][0];
  const int b = bh >> 4, h = bh & 15;
  const float C = 0.18033688011112042f;  // log2(e) / sqrt(dh)
  const f32x4 z = {0.f, 0.f, 0.f, 0.f};

  const int t0 = half * 16 + w;        // first owned 32-row q-tile
  const int t1 = half * 16 + 15 - w;   // second (balanced pairing)
  const int q0A = t0 * 32, q0B = t1 * 32;

  // staging thread mapping: row = tid>>3 (key for K, dh for V),
  // 16B-block = tid&7, global block pre-swizzled by row&7.
  const int srow = tid >> 3;
  const int sblk = (tid & 7) ^ (srow & 7);

#define STG_(s) {                                                              \
    const int bf__ = (s) % 3;                                                  \
    gl_lds16(Kb + (size_t)((s) * 64 + srow) * DH_ + sblk * 8, &lK[bf__][tid * 8]); \
    gl_lds16(Vb + (size_t)srow * S_ + (s) * 64 + sblk * 8, &lV[bf__][tid * 8]); }

  // Q fragments for both owned tiles: B[n=q(lr)][k=dh qd*8+j]
  bf16x8 bqA[2][2], bqB[2][2];
#pragma unroll
  for (int qt = 0; qt < 2; qt++)
#pragma unroll
    for (int kc = 0; kc < 2; kc++) {
      bqA[qt][kc] = ld8(Qb + (size_t)(q0A + qt * 16 + lr) * DH_ + kc * 32 + qd * 8);
      bqB[qt][kc] = ld8(Qb + (size_t)(q0B + qt * 16 + lr) * DH_ + kc * 32 + qd * 8);
    }

  f32x4 accA[4][2], accB[4][2];
#pragma unroll
  for (int i = 0; i < 4; i++)
#pragma unroll
    for (int j = 0; j < 2; j++) { accA[i][j] = z; accB[i][j] = z; }
  float liA[2] = {0.f, 0.f}, liB[2] = {0.f, 0.f};

  STG_(0); STG_(1);
  asm volatile("s_waitcnt vmcnt(2)" ::: "memory");  // step 0 landed, step 1 in flight
  FENCE(); __builtin_amdgcn_s_barrier(); FENCE();

#pragma unroll 1
  for (int s = 0; s < NS; ++s) {
    if (s + 2 < NS) STG_(s + 2);
    const ushort* cK = &lK[s % 3][0];
    const ushort* cV = &lV[s % 3][0];
    const int kb = s * 64;

    // shared fragment loads (swizzled): K A[m=key][k=dh], V A[m=dh][k=key]
    bf16x8 ak[4][2], av[4][2];
#pragma unroll
    for (int kt = 0; kt < 4; kt++)
#pragma unroll
      for (int kc = 0; kc < 2; kc++)
        ak[kt][kc] = ld8(cK + (kt * 16 + lr) * 64 + (((kc * 4 + qd) ^ (lr & 7)) << 3));
#pragma unroll
    for (int dt = 0; dt < 4; dt++)
#pragma unroll
      for (int kc = 0; kc < 2; kc++)
        av[dt][kc] = ld8(cV + (dt * 16 + lr) * 64 + (((kc * 4 + qd) ^ (lr & 7)) << 3));

#define TILE_(q0, bq, acc, li)                                                   \
    if (kb <= (q0) + 31) {                                                       \
      const bool diag = (kb + 64 > (q0));                                        \
      _Pragma("unroll")                                                          \
      for (int kt = 0; kt < 4; kt++) {                                           \
        const int keyb = kb + kt * 16 + qd * 4;                                  \
        _Pragma("unroll")                                                        \
        for (int qt = 0; qt < 2; qt++) {                                         \
          f32x4 sc = z;                                                          \
          sc = __builtin_amdgcn_mfma_f32_16x16x32_bf16(ak[kt][0], bq[qt][0], sc, 0, 0, 0); \
          sc = __builtin_amdgcn_mfma_f32_16x16x32_bf16(ak[kt][1], bq[qt][1], sc, 0, 0, 0); \
          const int qq = (q0) + qt * 16 + lr;                                    \
          float e0 = sc[0] * C, e1 = sc[1] * C, e2 = sc[2] * C, e3 = sc[3] * C;  \
          if (diag) {                                                            \
            e0 = (keyb + 0 <= qq) ? e0 : -1e30f;                                 \
            e1 = (keyb + 1 <= qq) ? e1 : -1e30f;                                 \
            e2 = (keyb + 2 <= qq) ? e2 : -1e30f;                                 \
            e3 = (keyb + 3 <= qq) ? e3 : -1e30f;                                 \
          }                                                                      \
          const float p0 = fast_exp2(e0), p1 = fast_exp2(e1);                    \
          const float p2 = fast_exp2(e2), p3 = fast_exp2(e3);                    \
          li[qt] += (p0 + p1) + (p2 + p3);                                       \
          const uint d0 = __builtin_amdgcn_perm(__builtin_bit_cast(uint, p1),    \
                                                __builtin_bit_cast(uint, p0), 0x07060302u); \
          const uint d1 = __builtin_amdgcn_perm(__builtin_bit_cast(uint, p3),    \
                                                __builtin_bit_cast(uint, p2), 0x07060302u); \
          uint2 pk; pk.x = d0; pk.y = d1;                                        \
          *(uint2*)(myP + (qt * 16 + lr) * PSTR_ + kt * 16 + qd * 4) = pk;       \
        }                                                                        \
      }                                                                          \
      _Pragma("unroll")                                                          \
      for (int qt = 0; qt < 2; qt++) {                                           \
        const bf16x8 bp0 = ld8(myP + (qt * 16 + lr) * PSTR_ + qd * 8);           \
        const bf16x8 bp1 = ld8(myP + (qt * 16 + lr) * PSTR_ + 32 + qd * 8);      \
        _Pragma("unroll")                                                        \
        for (int dt = 0; dt < 4; dt++) {                                         \
          acc[dt][qt] = __builtin_amdgcn_mfma_f32_16x16x32_bf16(av[dt][0], bp0, acc[dt][qt], 0, 0, 0); \
          acc[dt][qt] = __builtin_amdgcn_mfma_f32_16x16x32_bf16(av[dt][1], bp1, acc[dt][qt], 0, 0, 0); \
        }                                                                        \
      }                                                                          \
    }

    TILE_(q0A, bqA, accA, liA);
    TILE_(q0B, bqB, accB, liB);
#undef TILE_

    if (s + 2 < NS) { asm volatile("s_waitcnt vmcnt(2)" ::: "memory"); }
    else            { asm volatile("s_waitcnt vmcnt(0)" ::: "memory"); }
    FENCE(); __builtin_amdgcn_s_barrier(); FENCE();
  }
#undef STG_

  // epilogues
#define EPI_(q0, acc, li)                                                        \
  _Pragma("unroll")                                                              \
  for (int qt = 0; qt < 2; qt++) {                                               \
    float ssum = li[qt];                                                         \
    ssum += __shfl_xor(ssum, 16);                                                \
    ssum += __shfl_xor(ssum, 32);                                                \
    const float inv = 1.f / ssum;                                                \
    const int q = (q0) + qt * 16 + lr;                                           \
    ushort* orow = O + ((size_t)(b * S_ + q) * D_) + h * DH_ + qd * 4;           \
    _Pragma("unroll")                                                            \
    for (int dt = 0; dt < 4; dt++) {                                             \
      const f32x4 v = acc[dt][qt];                                               \
      uint2 pk;                                                                  \
      pk.x = (uint)f2bf(v[0] * inv) | ((uint)f2bf(v[1] * inv) << 16);            \
      pk.y = (uint)f2bf(v[2] * inv) | ((uint)f2bf(v[3] * inv) << 16);            \
      *(uint2*)(orow + dt * 16) = pk;                                            \
    }                                                                            \
  }

  EPI_(q0A, accA, liA);
  EPI_(q0B, accB, liB);
#undef EPI_
}

// ------------------------------------------------------------------- launch
extern "C" void kernel_launch(void* const* d_in, const int* in_sizes, int n_in,
                              void* d_out, int out_size, void* d_ws, size_t ws_size,
                              hipStream_t stream) {
  const float* x  = (const float*)d_in[0];
  const float* Wq = (const float*)d_in[1];
  const float* bq = (const float*)d_in[2];
  const float* Wk = (const float*)d_in[3];
  const float* bk = (const float*)d_in[4];
  const float* Wv = (const float*)d_in[5];
  const float* bv = (const float*)d_in[6];
  const float* Wo = (const float*)d_in[7];
  const float* bo = (const float*)d_in[8];
  float* out = (float*)d_out;

  char* ws = (char*)d_ws;
  ushort* xb   = (ushort*)(ws);                 // x bf16            32 MB
  ushort* qb   = (ushort*)(ws + 33554432);      // Q [B,H,S,dh]      32 MB
  ushort* kb   = (ushort*)(ws + 67108864);      // K [B,H,S,dh]      32 MB
  ushort* vtb  = (ushort*)(ws + 100663296);     // V [B,H,dh,S]      32 MB
  ushort* attn = (ushort*)(ws + 134217728);     // attn out [B,S,d]  32 MB
  ushort* wqb  = (ushort*)(ws + 167772160);     // Wq|Wk|Wv contiguous: [3072,1024]
  ushort* wkb  = (ushort*)(ws + 169869312);
  ushort* wvb  = (ushort*)(ws + 171966464);
  ushort* wob  = (ushort*)(ws + 174063616);

  cvt4<<<16384, 256, 0, stream>>>(x,  xb,  4194304);
  cvt4<<<1024,  256, 0, stream>>>(Wq, wqb, 262144);
  cvt4<<<1024,  256, 0, stream>>>(Wk, wkb, 262144);
  cvt4<<<1024,  256, 0, stream>>>(Wv, wvb, 262144);
  cvt4<<<1024,  256, 0, stream>>>(Wo, wob, 262144);

  gemm_qkv<<<768, 512, 0, stream>>>(xb, wqb, bq, bk, bv, qb, kb, vtb);

  attn_kernel<<<dim3(2, BH_), 512, 0, stream>>>(qb, kb, vtb, attn);

  gemm_out<<<256, 512, 0, stream>>>(attn, wob, bo, out);
}

// Round 4
// 377.056 us; speedup vs baseline: 1.1503x; 1.0992x over previous
//
#include <hip/hip_runtime.h>

// Problem constants: B=16, S=1024, d=1024, H=16, dh=64
#define B_  16
#define S_  1024
#define D_  1024
#define H_  16
#define DH_ 64
#define M_  (B_ * S_)    // 16384 rows in the projection GEMMs
#define BH_ (B_ * H_)    // 256 (b,h) pairs

typedef __attribute__((ext_vector_type(8))) __bf16 bf16x8;
typedef __attribute__((ext_vector_type(4))) float  f32x4;

__device__ __forceinline__ ushort f2bf(float f) {
  unsigned u = __builtin_bit_cast(unsigned, f);
  return (ushort)((u + 0x7FFFu + ((u >> 16) & 1u)) >> 16);
}

__device__ __forceinline__ bf16x8 ld8(const ushort* p) {
  return *(const bf16x8*)p;
}

__device__ __forceinline__ float fast_exp2(float x) {
  return __builtin_amdgcn_exp2f(x);  // v_exp_f32
}

__device__ __forceinline__ void gl_lds16(const void* g, void* s) {
  __builtin_amdgcn_global_load_lds((__attribute__((address_space(1))) void*)g,
                                   (__attribute__((address_space(3))) void*)s,
                                   16, 0, 0);
}

#define FENCE() asm volatile("" ::: "memory")

// ---------------------------------------------------------------- fp32->bf16
// All 5 conversions (x + 4 weight matrices) in ONE launch: inter-kernel gaps
// are ~3-5 us each; merging saves ~4 gaps of wall time.
__global__ void cvt_all(const float* __restrict__ x, const float* __restrict__ Wq,
                        const float* __restrict__ Wk, const float* __restrict__ Wv,
                        const float* __restrict__ Wo, ushort* __restrict__ xb,
                        ushort* __restrict__ wqb, ushort* __restrict__ wkb,
                        ushort* __restrict__ wvb, ushort* __restrict__ wob) {
  const int i = blockIdx.x * 256 + threadIdx.x;  // grid covers 5242880 float4s
  const float* s; ushort* d; int j;
  if (i < 4194304) { s = x; d = xb; j = i; }
  else {
    j = i - 4194304;
    const int w = j >> 18; j &= 262143;
    s = (w == 0) ? Wq : (w == 1) ? Wk : (w == 2) ? Wv : Wo;
    d = (w == 0) ? wqb : (w == 1) ? wkb : (w == 2) ? wvb : wob;
  }
  const float4 v = ((const float4*)s)[j];
  ushort4 o;
  o.x = f2bf(v.x); o.y = f2bf(v.y); o.z = f2bf(v.z); o.w = f2bf(v.w);
  ((ushort4*)d)[j] = o;
}

// =====================================================================
// 256x256 tile, BK=64, 8 waves (2M x 4N), 8-phase pipelined GEMM core.
// Verified r1/r3: SQ_LDS_BANK_CONFLICT = 0, passed, 141.6 us on qkv.
// =====================================================================
#define NT_ 16  // K = 1024 = 16 x BK(64)

// stage one half-tile (128 rows x 64 cols) = 2 x global_load_lds_dwordx4/thread
__device__ __forceinline__ void stg2(const ushort* __restrict__ src, ushort* lds,
                                     int bufop, int half, int kt,
                                     int wid, int lane, int rj0, int gcol) {
  gl_lds16(src + (size_t)(half * 128 + rj0) * 1024 + kt * 64 + gcol,
           lds + bufop * 16384 + half * 8192 + wid * 512 + lane * 8);
  gl_lds16(src + (size_t)(half * 128 + rj0 + 64) * 1024 + kt * 64 + gcol,
           lds + bufop * 16384 + half * 8192 + (wid + 8) * 512 + lane * 8);
}

__device__ __forceinline__ void gemm256_core(const ushort* __restrict__ baseA,
                                             const ushort* __restrict__ baseB,
                                             ushort* lds, f32x4 (&acc)[8][4]) {
  const int wid = threadIdx.x >> 6, lane = threadIdx.x & 63;
  const int lr = lane & 15, qd = lane >> 4;
  const int wr = wid >> 2, wc = wid & 3;
  const int gcol = ((lane & 7) ^ (lane >> 3)) << 3;  // pre-swizzled global col
  const int rj0  = wid * 8 + (lane >> 3);
  const int sw = lr & 7;
  const int colsw0 = (qd ^ sw) << 3;        // kk=0 swizzled 16B block
  const int colsw1 = ((4 + qd) ^ sw) << 3;  // kk=1

  // prologue: tile0 (A+B) -> buf0 ; B(tile1) -> buf1
  stg2(baseA, lds, 0, 0, 0, wid, lane, rj0, gcol);
  stg2(baseA, lds, 0, 1, 0, wid, lane, rj0, gcol);
  stg2(baseB, lds, 1, 0, 0, wid, lane, rj0, gcol);
  stg2(baseB, lds, 1, 1, 0, wid, lane, rj0, gcol);
  stg2(baseB, lds, 3, 0, 1, wid, lane, rj0, gcol);
  stg2(baseB, lds, 3, 1, 1, wid, lane, rj0, gcol);
  asm volatile("s_waitcnt vmcnt(4)" ::: "memory");  // tile0 landed; B(1) in flight
  FENCE(); __builtin_amdgcn_s_barrier(); FENCE();

#pragma unroll 1
  for (int t = 0; t < NT_; ++t) {
    const int cur = t & 1, nxt = cur ^ 1;
    const int cA = cur * 32768, cB = cA + 16384;
    bf16x8 bfr[4][2], afr[2][2];

#define LDA_(p)                                                                   \
    afr[0][0] = ld8(lds + cA + (wr * 128 + (2*(p)    ) * 16 + lr) * 64 + colsw0); \
    afr[0][1] = ld8(lds + cA + (wr * 128 + (2*(p)    ) * 16 + lr) * 64 + colsw1); \
    afr[1][0] = ld8(lds + cA + (wr * 128 + (2*(p) + 1) * 16 + lr) * 64 + colsw0); \
    afr[1][1] = ld8(lds + cA + (wr * 128 + (2*(p) + 1) * 16 + lr) * 64 + colsw1);

#define MFMA_(p)                                                             \
    FENCE(); __builtin_amdgcn_s_barrier();                                   \
    asm volatile("s_waitcnt lgkmcnt(0)" ::: "memory");                       \
    __builtin_amdgcn_s_setprio(1);                                           \
    _Pragma("unroll")                                                        \
    for (int j = 0; j < 4; j++) {                                            \
      acc[2*(p)  ][j] = __builtin_amdgcn_mfma_f32_16x16x32_bf16(afr[0][0], bfr[j][0], acc[2*(p)  ][j], 0, 0, 0); \
      acc[2*(p)  ][j] = __builtin_amdgcn_mfma_f32_16x16x32_bf16(afr[0][1], bfr[j][1], acc[2*(p)  ][j], 0, 0, 0); \
      acc[2*(p)+1][j] = __builtin_amdgcn_mfma_f32_16x16x32_bf16(afr[1][0], bfr[j][0], acc[2*(p)+1][j], 0, 0, 0); \
      acc[2*(p)+1][j] = __builtin_amdgcn_mfma_f32_16x16x32_bf16(afr[1][1], bfr[j][1], acc[2*(p)+1][j], 0, 0, 0); \
    }                                                                        \
    __builtin_amdgcn_s_setprio(0);

#define CLOSE_() FENCE(); __builtin_amdgcn_s_barrier(); FENCE();

    // ---- phase 0: read B-frags (tile t fully landed) + A m{0,1}; stage A-h0(t+1)
#pragma unroll
    for (int j = 0; j < 4; j++) {
      bfr[j][0] = ld8(lds + cB + (wc * 64 + j * 16 + lr) * 64 + colsw0);
      bfr[j][1] = ld8(lds + cB + (wc * 64 + j * 16 + lr) * 64 + colsw1);
    }
    LDA_(0);
    if (t + 1 < NT_) stg2(baseA, lds, nxt * 2, 0, t + 1, wid, lane, rj0, gcol);
    MFMA_(0); CLOSE_();
    // ---- phase 1: A m{2,3}; stage A-h1(t+1) then B-h0(t+2)
    LDA_(1);
    if (t + 1 < NT_) stg2(baseA, lds, nxt * 2, 1, t + 1, wid, lane, rj0, gcol);
    if (t + 2 < NT_) stg2(baseB, lds, cur * 2 + 1, 0, t + 2, wid, lane, rj0, gcol);
    MFMA_(1); CLOSE_();
    // ---- phase 2: A m{4,5}; stage B-h1(t+2)
    LDA_(2);
    if (t + 2 < NT_) stg2(baseB, lds, cur * 2 + 1, 1, t + 2, wid, lane, rj0, gcol);
    MFMA_(2); CLOSE_();
    // ---- phase 3: A m{6,7}; group-end counted vmcnt
    LDA_(3);
    MFMA_(3);
    if (t <= NT_ - 3) { asm volatile("s_waitcnt vmcnt(4)" ::: "memory"); }
    else              { asm volatile("s_waitcnt vmcnt(0)" ::: "memory"); }
    CLOSE_();
#undef LDA_
#undef MFMA_
#undef CLOSE_
  }
}

// ------------------------------------------------------- fused QKV projection
__global__ __launch_bounds__(512, 2) void gemm_qkv(
    const ushort* __restrict__ A, const ushort* __restrict__ Wqkv,
    const float* __restrict__ bqp, const float* __restrict__ bkp,
    const float* __restrict__ bvp, ushort* __restrict__ qO,
    ushort* __restrict__ kO, ushort* __restrict__ vtO) {
  __shared__ ushort lds[65536];  // 128 KiB
  int wg = blockIdx.x;
  wg = (wg & 7) * 96 + (wg >> 3);  // XCD swizzle: 768 wgs, 96/XCD
  const int mb = wg / 12, nb = wg % 12;
  const int wid = threadIdx.x >> 6, lane = threadIdx.x & 63;
  const int lr = lane & 15, qd = lane >> 4;
  const int wr = wid >> 2, wc = wid & 3;

  f32x4 acc[8][4];
  const f32x4 z = {0.f, 0.f, 0.f, 0.f};
#pragma unroll
  for (int i = 0; i < 8; i++)
#pragma unroll
    for (int j = 0; j < 4; j++) acc[i][j] = z;

  gemm256_core(A + (size_t)(mb * 256) * 1024, Wqkv + (size_t)(nb * 256) * 1024, lds, acc);

  const int proj = nb >> 2;  // block-uniform
  const float* bias = (proj == 0) ? bqp : (proj == 1) ? bkp : bvp;
  ushort* outH = (proj == 0) ? qO : (proj == 1) ? kO : vtO;
  const int m0 = mb * 256;

#pragma unroll
  for (int j = 0; j < 4; j++) {
    const int nn = (nb * 256 + wc * 64 + j * 16 + lr) & 1023;
    const float bv = bias[nn];
    const int h = nn >> 6, dc = nn & 63;
#pragma unroll
    for (int i = 0; i < 8; i++) {
      const f32x4 v = acc[i][j];
      const int mbase = m0 + wr * 128 + i * 16 + qd * 4;
      const int b = mbase >> 10, s0 = mbase & 1023;
      if (proj < 2) {
#pragma unroll
        for (int r = 0; r < 4; r++)
          outH[((size_t)(b * H_ + h) * S_ + s0 + r) * DH_ + dc] = f2bf(v[r] + bv);
      } else {
        uint2 pk;
        pk.x = (uint)f2bf(v[0] + bv) | ((uint)f2bf(v[1] + bv) << 16);
        pk.y = (uint)f2bf(v[2] + bv) | ((uint)f2bf(v[3] + bv) << 16);
        *(uint2*)&outH[((size_t)(b * H_ + h) * DH_ + dc) * S_ + s0] = pk;
      }
    }
  }
}

// ------------------------------------------------------------- output GEMM
__global__ __launch_bounds__(512, 2) void gemm_out(
    const ushort* __restrict__ A, const ushort* __restrict__ W,
    const float* __restrict__ bias, float* __restrict__ outF) {
  __shared__ ushort lds[65536];
  int wg = blockIdx.x;
  wg = (wg & 7) * 32 + (wg >> 3);  // 256 wgs, 32/XCD
  const int mb = wg >> 2, nb = wg & 3;
  const int wid = threadIdx.x >> 6, lane = threadIdx.x & 63;
  const int lr = lane & 15, qd = lane >> 4;
  const int wr = wid >> 2, wc = wid & 3;

  f32x4 acc[8][4];
  const f32x4 z = {0.f, 0.f, 0.f, 0.f};
#pragma unroll
  for (int i = 0; i < 8; i++)
#pragma unroll
    for (int j = 0; j < 4; j++) acc[i][j] = z;

  gemm256_core(A + (size_t)(mb * 256) * 1024, W + (size_t)(nb * 256) * 1024, lds, acc);

#pragma unroll
  for (int j = 0; j < 4; j++) {
    const int n = nb * 256 + wc * 64 + j * 16 + lr;
    const float bv = bias[n];
#pragma unroll
    for (int i = 0; i < 8; i++) {
      const f32x4 v = acc[i][j];
      const int m = mb * 256 + wr * 128 + i * 16 + qd * 4;
#pragma unroll
      for (int r = 0; r < 4; r++) outF[(size_t)(m + r) * D_ + n] = v[r] + bv;
    }
  }
}

// --------------------------------------------------------------- attention
// r1's proven barrier-free causal flash attention (transposed-score
// formulation, balanced wave pairing {p, 15-p}) with ONE change: XCD-
// clustered bh assignment. All 512 blocks are co-resident (2 blocks/CU);
// with the default linear mapping each XCD's 64 blocks span ~64 distinct
// (b,h) = 16 MB of K/V vs its 4 MB L2 -> near-zero L2 hits, K/V re-fetch
// at L3 latency/BW is the bottleneck. Remap so XCD x serves bh in
// [32x, 32x+32): working set 8 MB, disjoint across XCDs.
#define PSTR 40  // LDS row stride (ushorts): 80B, 16B-aligned
__global__ __launch_bounds__(256) void attn_kernel(
    const ushort* __restrict__ Q, const ushort* __restrict__ K,
    const ushort* __restrict__ Vt, ushort* __restrict__ O) {
  __shared__ ushort lP[4][64 * PSTR];
  const int id = blockIdx.x;           // 0..511, dispatch round-robins XCDs
  const int xcd = id & 7, jj = id >> 3;  // jj 0..63
  const int bh = xcd * 32 + (jj & 31);   // 32 bh per XCD
  const int halfsel = jj >> 5;           // 0/1
  const int w = threadIdx.x >> 6, l = threadIdx.x & 63;
  const int lr = l & 15, qd = l >> 4;
  const int p = halfsel * 4 + w;  // 0..7
  const size_t base = (size_t)bh * (S_ * DH_);
  const ushort* Qb = Q + base;
  const ushort* Kb = K + base;
  const ushort* Vb = Vt + (size_t)bh * (DH_ * S_);
  ushort* myP = &lP[w][0];
  const int b = bh >> 4, h = bh & 15;
  const float C = 0.18033688011112042f;  // log2(e) / sqrt(dh)
  const f32x4 z = {0.f, 0.f, 0.f, 0.f};

#pragma unroll 1
  for (int tt = 0; tt < 2; tt++) {
    const int q0 = (tt == 0 ? p : 15 - p) * 64;

    // Q B-fragments: B[n=q(lane&15)][k=dh qd*8+j]
    bf16x8 bq[4][2];
#pragma unroll
    for (int qt = 0; qt < 4; qt++)
#pragma unroll
      for (int kc = 0; kc < 2; kc++)
        bq[qt][kc] = ld8(Qb + (size_t)(q0 + qt * 16 + lr) * DH_ + kc * 32 + qd * 8);

    f32x4 acc[4][4];  // [dh tile][q tile], O^T C-layout
#pragma unroll
    for (int i = 0; i < 4; i++)
#pragma unroll
      for (int j = 0; j < 4; j++) acc[i][j] = z;
    float li[4] = {0.f, 0.f, 0.f, 0.f};

    for (int kb = 0; kb < q0 + 64; kb += 32) {
      // K A-frags: A[m=key local][k=dh]
      bf16x8 ak[2][2];
#pragma unroll
      for (int kt = 0; kt < 2; kt++)
#pragma unroll
        for (int kc = 0; kc < 2; kc++)
          ak[kt][kc] = ld8(Kb + (size_t)(kb + kt * 16 + lr) * DH_ + kc * 32 + qd * 8);
      // V A-frags: A[m=dh local][k=key]
      bf16x8 av[4];
#pragma unroll
      for (int dt = 0; dt < 4; dt++)
        av[dt] = ld8(Vb + (size_t)(dt * 16 + lr) * S_ + kb + qd * 8);

      const bool diag = (kb + 31 >= q0);  // wave-uniform
#pragma unroll
      for (int kt = 0; kt < 2; kt++) {
        const int keyb = kb + kt * 16 + qd * 4;
#pragma unroll
        for (int qt = 0; qt < 4; qt++) {
          f32x4 s = z;
          s = __builtin_amdgcn_mfma_f32_16x16x32_bf16(ak[kt][0], bq[qt][0], s, 0, 0, 0);
          s = __builtin_amdgcn_mfma_f32_16x16x32_bf16(ak[kt][1], bq[qt][1], s, 0, 0, 0);
          const int qq = q0 + qt * 16 + lr;
          float e0 = s[0] * C, e1 = s[1] * C, e2 = s[2] * C, e3 = s[3] * C;
          if (diag) {
            e0 = (keyb + 0 <= qq) ? e0 : -1e30f;
            e1 = (keyb + 1 <= qq) ? e1 : -1e30f;
            e2 = (keyb + 2 <= qq) ? e2 : -1e30f;
            e3 = (keyb + 3 <= qq) ? e3 : -1e30f;
          }
          const float p0 = fast_exp2(e0), p1 = fast_exp2(e1);
          const float p2 = fast_exp2(e2), p3 = fast_exp2(e3);
          li[qt] += (p0 + p1) + (p2 + p3);
          const uint d0 = __builtin_amdgcn_perm(__builtin_bit_cast(uint, p1),
                                                __builtin_bit_cast(uint, p0), 0x07060302u);
          const uint d1 = __builtin_amdgcn_perm(__builtin_bit_cast(uint, p3),
                                                __builtin_bit_cast(uint, p2), 0x07060302u);
          uint2 pk; pk.x = d0; pk.y = d1;
          *(uint2*)(myP + (qt * 16 + lr) * PSTR + kt * 16 + qd * 4) = pk;
        }
      }
      // PV: B[n=q][k=key] from wave-private LDS
#pragma unroll
      for (int qt = 0; qt < 4; qt++) {
        const bf16x8 bp = ld8(myP + (qt * 16 + lr) * PSTR + qd * 8);
#pragma unroll
        for (int dt = 0; dt < 4; dt++)
          acc[dt][qt] = __builtin_amdgcn_mfma_f32_16x16x32_bf16(av[dt], bp, acc[dt][qt], 0, 0, 0);
      }
    }

    // epilogue for this tile
#pragma unroll
    for (int qt = 0; qt < 4; qt++) {
      float s = li[qt];
      s += __shfl_xor(s, 16);
      s += __shfl_xor(s, 32);
      const float inv = 1.f / s;
      const int q = q0 + qt * 16 + lr;
      ushort* orow = O + ((size_t)(b * S_ + q) * D_) + h * DH_ + qd * 4;
#pragma unroll
      for (int dt = 0; dt < 4; dt++) {
        const f32x4 v = acc[dt][qt];
        uint2 pk;
        pk.x = (uint)f2bf(v[0] * inv) | ((uint)f2bf(v[1] * inv) << 16);
        pk.y = (uint)f2bf(v[2] * inv) | ((uint)f2bf(v[3] * inv) << 16);
        *(uint2*)(orow + dt * 16) = pk;
      }
    }
  }
}

// ------------------------------------------------------------------- launch
extern "C" void kernel_launch(void* const* d_in, const int* in_sizes, int n_in,
                              void* d_out, int out_size, void* d_ws, size_t ws_size,
                              hipStream_t stream) {
  const float* x  = (const float*)d_in[0];
  const float* Wq = (const float*)d_in[1];
  const float* bq = (const float*)d_in[2];
  const float* Wk = (const float*)d_in[3];
  const float* bk = (const float*)d_in[4];
  const float* Wv = (const float*)d_in[5];
  const float* bv = (const float*)d_in[6];
  const float* Wo = (const float*)d_in[7];
  const float* bo = (const float*)d_in[8];
  float* out = (float*)d_out;

  char* ws = (char*)d_ws;
  ushort* xb   = (ushort*)(ws);                 // x bf16            32 MB
  ushort* qb   = (ushort*)(ws + 33554432);      // Q [B,H,S,dh]      32 MB
  ushort* kb   = (ushort*)(ws + 67108864);      // K [B,H,S,dh]      32 MB
  ushort* vtb  = (ushort*)(ws + 100663296);     // V [B,H,dh,S]      32 MB
  ushort* attn = (ushort*)(ws + 134217728);     // attn out [B,S,d]  32 MB
  ushort* wqb  = (ushort*)(ws + 167772160);     // Wq|Wk|Wv contiguous: [3072,1024]
  ushort* wkb  = (ushort*)(ws + 169869312);
  ushort* wvb  = (ushort*)(ws + 171966464);
  ushort* wob  = (ushort*)(ws + 174063616);

  cvt_all<<<20480, 256, 0, stream>>>(x, Wq, Wk, Wv, Wo, xb, wqb, wkb, wvb, wob);

  gemm_qkv<<<768, 512, 0, stream>>>(xb, wqb, bq, bk, bv, qb, kb, vtb);

  attn_kernel<<<512, 256, 0, stream>>>(qb, kb, vtb, attn);

  gemm_out<<<256, 512, 0, stream>>>(attn, wob, bo, out);
}